// Round 9
// baseline (261.506 us; speedup 1.0000x reference)
//
#include <hip/hip_runtime.h>
#include <hip/hip_bf16.h>
#include <math.h>

#define T_SEQ 4096
#define C_DIM 1024
#define H_HEADS 16
#define D_HEAD 64
#define QKVW 3072
#define WIN_HALF 128
#define GLOBAL_TOK 32

typedef __attribute__((ext_vector_type(8))) short bf16x8;
typedef __attribute__((ext_vector_type(4))) float f32x4;

__device__ __forceinline__ float bf2f(unsigned short u) {
    union { unsigned int i; float f; } c; c.i = ((unsigned int)u) << 16; return c.f;
}
__device__ __forceinline__ unsigned short f2bf(float f) {
    union { float f; unsigned int i; } c; c.f = f;
    return (unsigned short)((c.i + 0x7fffu + ((c.i >> 16) & 1u)) >> 16);
}

__device__ __forceinline__ void gll16(const unsigned short* g, unsigned short* l) {
    __builtin_amdgcn_global_load_lds(
        (const __attribute__((address_space(1))) void*)g,
        (__attribute__((address_space(3))) void*)l, 16, 0, 0);
}

// f32 -> bf16 (RNE), vectorized x4. n4 = n/4.
__global__ __launch_bounds__(256) void cvt_f32_bf16_kernel(
    const float* __restrict__ src, unsigned short* __restrict__ dst, int n4)
{
    int idx = blockIdx.x * 256 + threadIdx.x;
    if (idx < n4) {
        float4 v = ((const float4*)src)[idx];
        ushort4 o;
        o.x = f2bf(v.x); o.y = f2bf(v.y); o.z = f2bf(v.z); o.w = f2bf(v.w);
        ((ushort4*)dst)[idx] = o;
    }
}

// W [R][Ncols] f32  ->  Wt [Ncols][R] bf16  (32x32 tiles via LDS)
__global__ __launch_bounds__(256) void cvt_transpose_kernel(
    const float* __restrict__ src, unsigned short* __restrict__ dst,
    int R, int Ncols)
{
    __shared__ unsigned short tile[32][36];
    const int r0 = blockIdx.y * 32, c0 = blockIdx.x * 32;
    const int t = threadIdx.x;
    const int rr = t >> 3, cq = (t & 7) * 4;
    float4 v = *(const float4*)(src + (size_t)(r0 + rr) * Ncols + c0 + cq);
    tile[rr][cq + 0] = f2bf(v.x); tile[rr][cq + 1] = f2bf(v.y);
    tile[rr][cq + 2] = f2bf(v.z); tile[rr][cq + 3] = f2bf(v.w);
    __syncthreads();
    const int cc = t >> 3, rq = (t & 7) * 4;
    ushort4 o;
    o.x = tile[rq + 0][cc]; o.y = tile[rq + 1][cc];
    o.z = tile[rq + 2][cc]; o.w = tile[rq + 3][cc];
    *(ushort4*)(dst + (size_t)(c0 + cc) * R + r0 + rq) = o;
}

// V slice of qkv [T][2048 + vcol] (bf16) -> vT [vcol][T] (bf16), 32x32 tiles.
__global__ __launch_bounds__(256) void transpose_v_kernel(
    const unsigned short* __restrict__ qkv, unsigned short* __restrict__ vT)
{
    __shared__ unsigned short tile[32][36];
    const int c0 = blockIdx.x * 32;   // vcol
    const int t0 = blockIdx.y * 32;   // token
    const int t = threadIdx.x;
    const int rr = t >> 3, cq = (t & 7) * 4;
    ushort4 v = *(const ushort4*)(qkv + (size_t)(t0 + rr) * QKVW + 2 * C_DIM + c0 + cq);
    tile[rr][cq + 0] = v.x; tile[rr][cq + 1] = v.y;
    tile[rr][cq + 2] = v.z; tile[rr][cq + 3] = v.w;
    __syncthreads();
    const int cc = t >> 3, rq = (t & 7) * 4;
    ushort4 o;
    o.x = tile[rq + 0][cc]; o.y = tile[rq + 1][cc];
    o.z = tile[rq + 2][cc]; o.w = tile[rq + 3][cc];
    *(ushort4*)(vT + (size_t)(c0 + cc) * T_SEQ + t0 + rq) = o;
}

// C[m,n] = sum_k A[m,k]*Bt[n,k] + bias[n]; m97 recipe (unchanged r7/r8).
template<int OUT_BF16>
__global__ __launch_bounds__(256) void gemm_nt_kernel(
    const unsigned short* __restrict__ A,    // [M,K]
    const unsigned short* __restrict__ Bt,   // [N,K]
    const float* __restrict__ bias,          // [N]
    void* __restrict__ Cv, int M, int N, int K)
{
    __shared__ unsigned short As[128 * 32];
    __shared__ unsigned short Bs[128 * 32];
    const int tid = threadIdx.x;
    const int w = tid >> 6, lane = tid & 63;
    const int quad = lane >> 4, r16 = lane & 15;
    const int m0 = blockIdx.y * 128, n0 = blockIdx.x * 128;
    const int wm = (w & 1) * 64, wn = (w >> 1) * 64;

    f32x4 acc[4][4];
    #pragma unroll
    for (int i = 0; i < 4; ++i)
        #pragma unroll
        for (int j = 0; j < 4; ++j) acc[i][j] = (f32x4){0.f, 0.f, 0.f, 0.f};

    const unsigned short* Ab = A + (size_t)m0 * K;
    const unsigned short* Bb = Bt + (size_t)n0 * K;

    for (int k0 = 0; k0 < K; k0 += 32) {
        __syncthreads();
        #pragma unroll
        for (int i = 0; i < 2; ++i) {
            const int chunk = w * 128 + i * 64 + lane;
            const int row = chunk >> 2, kc = (chunk & 3) * 8;
            gll16(Ab + (size_t)row * K + k0 + kc, &As[(w * 2 + i) * 512]);
            gll16(Bb + (size_t)row * K + k0 + kc, &Bs[(w * 2 + i) * 512]);
        }
        asm volatile("s_waitcnt vmcnt(0)" ::: "memory");
        __syncthreads();

        bf16x8 af[4], bf_[4];
        #pragma unroll
        for (int t = 0; t < 4; ++t) {
            af[t]  = *(const bf16x8*)&As[(wm + t * 16 + r16) * 32 + quad * 8];
            bf_[t] = *(const bf16x8*)&Bs[(wn + t * 16 + r16) * 32 + quad * 8];
        }
        #pragma unroll
        for (int mt = 0; mt < 4; ++mt)
            #pragma unroll
            for (int nt = 0; nt < 4; ++nt)
                acc[mt][nt] = __builtin_amdgcn_mfma_f32_16x16x32_bf16(
                    af[mt], bf_[nt], acc[mt][nt], 0, 0, 0);
    }

    #pragma unroll
    for (int nt = 0; nt < 4; ++nt) {
        const int col = n0 + wn + nt * 16 + r16;
        const float bv = bias[col];
        #pragma unroll
        for (int mt = 0; mt < 4; ++mt)
            #pragma unroll
            for (int reg = 0; reg < 4; ++reg) {
                const int row = m0 + wm + mt * 16 + quad * 4 + reg;
                if (OUT_BF16)
                    ((unsigned short*)Cv)[(size_t)row * N + col] = f2bf(acc[mt][nt][reg] + bv);
                else
                    ((float*)Cv)[(size_t)row * N + col] = acc[mt][nt][reg] + bv;
            }
    }
}

// MFMA flash attention, LDS-staging-free, 64-col tiles, register prefetch,
// XCD-aware head swizzle (head ≡ bid mod 8 -> per-XCD L2 keeps 2 heads' K/V).
// Block = (head, 16-row tile); 4 waves share rows, tile-split; K/V^T frags
// load directly from global (b128). P C->A layout via per-wave LDS.
// Normal (rows>=32): tile 0 = cols [0,64) + window tiles from max(64, lo&~63);
//   unified mask col<32 || |row-col|<=128; end-of-block 4-wave LDS merge.
// Dense (rows 0-31, all cols valid): 8 splits x 4 waves x 2 tiles; partial
//   (m,l,O) per wave -> slot split*4+w; merged by attn_combine.
#define PT_STRIDE 72
#define NSLOT 32
#define PROW 72
__global__ __launch_bounds__(256) void sparse_attn_mfma(
    const unsigned short* __restrict__ qkv,
    const unsigned short* __restrict__ vT,
    unsigned short* __restrict__ y,
    float* __restrict__ part)
{
    __shared__ float Om[4][64][17];
    __shared__ float Ml[4][16][2];
    __shared__ unsigned short Pt[4][16 * PT_STRIDE];

    const int tid = threadIdx.x;
    const int w = tid >> 6, lane = tid & 63;
    const int quad = lane >> 4, n = lane & 15;
    const int bid = blockIdx.x;
    const int nNormal = H_HEADS * 254;

    int h, rt, split = -1;
    if (bid < nNormal) {
        const int xcd = bid & 7, j = bid >> 3;         // j in [0,508)
        h = xcd + 8 * (j & 1);
        rt = 2 + (j >> 1);
    } else {
        const int idx = bid - nNormal;                 // [0,256)
        const int xcd = idx & 7, j = idx >> 3;         // j in [0,32)
        h = xcd + 8 * (j & 1);
        const int rest = j >> 1;                       // [0,16)
        rt = rest & 1; split = rest >> 1;              // split in [0,8)
    }
    const bool dense = split >= 0;
    const int rowbase = rt * 16;

    // Q A-frags (A[m=lane&15][k=quad*8+j])
    const unsigned short* qptr = qkv + (size_t)(rowbase + n) * QKVW + h * 64 + quad * 8;
    bf16x8 a0 = *(const bf16x8*)qptr;
    bf16x8 a1 = *(const bf16x8*)(qptr + 32);

    f32x4 O[4];
    #pragma unroll
    for (int i = 0; i < 4; ++i) O[i] = (f32x4){0.f, 0.f, 0.f, 0.f};
    float m_run[4], l_run[4];
    #pragma unroll
    for (int r = 0; r < 4; ++r) { m_run[r] = -INFINITY; l_run[r] = 0.f; }

    const unsigned short* kb = qkv + C_DIM + h * 64;
    const unsigned short* vb = vT + (size_t)h * 64 * T_SEQ;

    // per-wave tile list (<= 2 tiles of 64 cols)
    int c0s[2]; int cnt = 0;
    if (dense) {
        c0s[0] = (split * 8 + w * 2) * 64;
        c0s[1] = c0s[0] + 64;
        cnt = 2;
    } else {
        int wlo64 = (rowbase - WIN_HALF) & ~63; if (wlo64 < 64) wlo64 = 64;
        int whi = rowbase + 16 + WIN_HALF; if (whi > T_SEQ) whi = T_SEQ;
        const int n_tiles = 1 + (whi > wlo64 ? (whi - wlo64 + 63) / 64 : 0);
        for (int it = w; it < n_tiles && cnt < 2; it += 4)
            c0s[cnt++] = (it == 0) ? 0 : wlo64 + (it - 1) * 64;
    }

    bf16x8 kf[8];
    if (cnt) {
        const unsigned short* kr = kb + (size_t)(c0s[0] + n) * QKVW + quad * 8;
        #pragma unroll
        for (int g = 0; g < 4; ++g) {
            kf[g * 2 + 0] = *(const bf16x8*)(kr + (size_t)g * 16 * QKVW);
            kf[g * 2 + 1] = *(const bf16x8*)(kr + (size_t)g * 16 * QKVW + 32);
        }
    }

    for (int i = 0; i < cnt; ++i) {
        const int c0 = c0s[i];
        // ---- S = Q K^T, 64 cols (4 col-groups) ----
        f32x4 Z = (f32x4){0.f, 0.f, 0.f, 0.f};
        f32x4 S[4];
        #pragma unroll
        for (int g = 0; g < 4; ++g) {
            S[g] = __builtin_amdgcn_mfma_f32_16x16x32_bf16(a0, kf[g * 2 + 0], Z, 0, 0, 0);
            S[g] = __builtin_amdgcn_mfma_f32_16x16x32_bf16(a1, kf[g * 2 + 1], S[g], 0, 0, 0);
        }
        // ---- prefetch next tile's K frags + this tile's V frags (MLP) ----
        bf16x8 kfn[8];
        if (i + 1 < cnt) {
            const unsigned short* kr = kb + (size_t)(c0s[i + 1] + n) * QKVW + quad * 8;
            #pragma unroll
            for (int g = 0; g < 4; ++g) {
                kfn[g * 2 + 0] = *(const bf16x8*)(kr + (size_t)g * 16 * QKVW);
                kfn[g * 2 + 1] = *(const bf16x8*)(kr + (size_t)g * 16 * QKVW + 32);
            }
        }
        bf16x8 vf[8];
        {
            const unsigned short* vr = vb + (size_t)n * T_SEQ + c0 + quad * 8;
            #pragma unroll
            for (int d = 0; d < 4; ++d) {
                vf[d * 2 + 0] = *(const bf16x8*)(vr + (size_t)d * 16 * T_SEQ);
                vf[d * 2 + 1] = *(const bf16x8*)(vr + (size_t)d * 16 * T_SEQ + 32);
            }
        }

        // ---- mask + online softmax per row ----
        float alpha[4];
        #pragma unroll
        for (int r = 0; r < 4; ++r) {
            float s[4];
            #pragma unroll
            for (int g = 0; g < 4; ++g) {
                s[g] = S[g][r] * 0.125f;
                if (!dense) {
                    const int row = rowbase + quad * 4 + r;
                    const int cc = c0 + g * 16 + n;
                    int d = row - cc; d = d < 0 ? -d : d;
                    if (!(cc < GLOBAL_TOK || d <= WIN_HALF)) s[g] = -INFINITY;
                }
            }
            float mm = fmaxf(fmaxf(s[0], s[1]), fmaxf(s[2], s[3]));
            #pragma unroll
            for (int off = 1; off < 16; off <<= 1)
                mm = fmaxf(mm, __shfl_xor(mm, off));
            const float mn = fmaxf(m_run[r], mm);
            const float mnf = (mn == -INFINITY) ? 0.f : mn;
            const float al = __expf(m_run[r] - mnf);
            float e[4], rs = 0.f;
            #pragma unroll
            for (int g = 0; g < 4; ++g) { e[g] = __expf(s[g] - mnf); rs += e[g]; }
            #pragma unroll
            for (int off = 1; off < 16; off <<= 1)
                rs += __shfl_xor(rs, off);
            l_run[r] = l_run[r] * al + rs;
            m_run[r] = mn;
            alpha[r] = al;
            #pragma unroll
            for (int g = 0; g < 4; ++g)
                Pt[w][(quad * 4 + r) * PT_STRIDE + g * 16 + n] = f2bf(e[g]);
        }
        #pragma unroll
        for (int dblk = 0; dblk < 4; ++dblk)
            #pragma unroll
            for (int r = 0; r < 4; ++r)
                O[dblk][r] *= alpha[r];

        asm volatile("s_waitcnt lgkmcnt(0)" ::: "memory");
        // ---- PV: P[16x64] x V[64x64] ----
        bf16x8 pf0 = *(bf16x8*)&Pt[w][n * PT_STRIDE + quad * 8];
        bf16x8 pf1 = *(bf16x8*)&Pt[w][n * PT_STRIDE + 32 + quad * 8];
        #pragma unroll
        for (int dblk = 0; dblk < 4; ++dblk) {
            O[dblk] = __builtin_amdgcn_mfma_f32_16x16x32_bf16(pf0, vf[dblk * 2 + 0], O[dblk], 0, 0, 0);
            O[dblk] = __builtin_amdgcn_mfma_f32_16x16x32_bf16(pf1, vf[dblk * 2 + 1], O[dblk], 0, 0, 0);
        }
        #pragma unroll
        for (int q = 0; q < 8; ++q) kf[q] = kfn[q];
    }

    if (dense) {
        const int slot = split * 4 + w;
        float* pb = part + ((size_t)(h * 2 + rt) * NSLOT + slot) * 16 * PROW;
        #pragma unroll
        for (int dblk = 0; dblk < 4; ++dblk)
            #pragma unroll
            for (int r = 0; r < 4; ++r)
                pb[(quad * 4 + r) * PROW + dblk * 16 + n] = O[dblk][r];
        if (n == 0) {
            #pragma unroll
            for (int r = 0; r < 4; ++r) {
                pb[(quad * 4 + r) * PROW + 64] = m_run[r];
                pb[(quad * 4 + r) * PROW + 65] = l_run[r];
            }
        }
    } else {
        #pragma unroll
        for (int dblk = 0; dblk < 4; ++dblk)
            #pragma unroll
            for (int r = 0; r < 4; ++r)
                Om[w][lane][dblk * 4 + r] = O[dblk][r];
        if (n == 0) {
            #pragma unroll
            for (int r = 0; r < 4; ++r) {
                Ml[w][quad * 4 + r][0] = m_run[r];
                Ml[w][quad * 4 + r][1] = l_run[r];
            }
        }
        __syncthreads();
        if (w == 0) {
            #pragma unroll
            for (int r = 0; r < 4; ++r) {
                const int row = quad * 4 + r;
                float M = -INFINITY;
                #pragma unroll
                for (int ww = 0; ww < 4; ++ww)
                    M = fmaxf(M, Ml[ww][row][0]);
                float e[4], L = 0.f;
                #pragma unroll
                for (int ww = 0; ww < 4; ++ww) {
                    e[ww] = __expf(Ml[ww][row][0] - M);
                    L += Ml[ww][row][1] * e[ww];
                }
                const float invL = 1.f / L;
                #pragma unroll
                for (int dblk = 0; dblk < 4; ++dblk) {
                    float v = 0.f;
                    #pragma unroll
                    for (int ww = 0; ww < 4; ++ww)
                        v += Om[ww][lane][dblk * 4 + r] * e[ww];
                    y[(size_t)(rowbase + row) * C_DIM + h * 64 + dblk * 16 + n] =
                        f2bf(v * invL);
                }
            }
        }
    }
}

// Merge NSLOT partials per (head, 16-row tile) -> y rows 0..31.
__global__ __launch_bounds__(64) void attn_combine(
    const float* __restrict__ part, unsigned short* __restrict__ y)
{
    const int d = threadIdx.x;
    const int h = blockIdx.x >> 1, rt = blockIdx.x & 1;
    const float* base = part + (size_t)(h * 2 + rt) * NSLOT * 16 * PROW;
    for (int row = 0; row < 16; ++row) {
        float M = -INFINITY;
        for (int sl = 0; sl < NSLOT; ++sl)
            M = fmaxf(M, base[(size_t)sl * 16 * PROW + row * PROW + 64]);
        float L = 0.f, Od = 0.f;
        for (int sl = 0; sl < NSLOT; ++sl) {
            const float* p = base + (size_t)sl * 16 * PROW + row * PROW;
            const float s = __expf(p[64] - M);
            L += p[65] * s;
            Od += p[d] * s;
        }
        y[(size_t)(rt * 16 + row) * C_DIM + h * 64 + d] = f2bf(Od / L);
    }
}

extern "C" void kernel_launch(void* const* d_in, const int* in_sizes, int n_in,
                              void* d_out, int out_size, void* d_ws, size_t ws_size,
                              hipStream_t stream) {
    const float* x  = (const float*)d_in[0];
    const float* Wa = (const float*)d_in[1];
    const float* ba = (const float*)d_in[2];
    const float* Wp = (const float*)d_in[3];
    const float* bp = (const float*)d_in[4];
    float* out = (float*)d_out;

    // ws (ushort units): xb 4M, Wabt 3M, Wpbt 1M, qkv 12M, yat 4M = 48 MiB
    unsigned short* xb   = (unsigned short*)d_ws;                   // [4096,1024]
    unsigned short* Wabt = xb   + (size_t)T_SEQ * C_DIM;            // [3072,1024]
    unsigned short* Wpbt = Wabt + (size_t)C_DIM * QKVW;             // [1024,1024]
    unsigned short* qkv  = Wpbt + (size_t)C_DIM * C_DIM;            // [4096,3072]
    unsigned short* yat  = qkv  + (size_t)T_SEQ * QKVW;             // [4096,1024]
    // overlays (dead after gemm1): vT on xb (8 MiB), part on Wabt (4.7 MB)
    unsigned short* vT = xb;
    float* part = (float*)Wabt;

    const int n_x = T_SEQ * C_DIM;
    cvt_f32_bf16_kernel<<<n_x / 4 / 256, 256, 0, stream>>>(x, xb, n_x / 4);
    cvt_transpose_kernel<<<dim3(QKVW / 32, C_DIM / 32), 256, 0, stream>>>(
        Wa, Wabt, C_DIM, QKVW);
    cvt_transpose_kernel<<<dim3(C_DIM / 32, C_DIM / 32), 256, 0, stream>>>(
        Wp, Wpbt, C_DIM, C_DIM);

    gemm_nt_kernel<1><<<dim3(QKVW / 128, T_SEQ / 128), 256, 0, stream>>>(
        xb, Wabt, ba, qkv, T_SEQ, QKVW, C_DIM);

    transpose_v_kernel<<<dim3(C_DIM / 32, T_SEQ / 32), 256, 0, stream>>>(qkv, vT);

    const int nBlocks = H_HEADS * 254 + H_HEADS * 16;   // 4064 normal + 256 dense
    sparse_attn_mfma<<<nBlocks, 256, 0, stream>>>(qkv, vT, yat, part);
    attn_combine<<<H_HEADS * 2, 64, 0, stream>>>(part, yat);

    gemm_nt_kernel<0><<<dim3(C_DIM / 128, T_SEQ / 128), 256, 0, stream>>>(
        yat, Wpbt, bp, out, T_SEQ, C_DIM, C_DIM);
}

// Round 10
// 237.400 us; speedup vs baseline: 1.1015x; 1.1015x over previous
//
#include <hip/hip_runtime.h>
#include <hip/hip_bf16.h>
#include <math.h>

#define T_SEQ 4096
#define C_DIM 1024
#define H_HEADS 16
#define D_HEAD 64
#define QKVW 3072
#define WIN_HALF 128
#define GLOBAL_TOK 32

typedef __attribute__((ext_vector_type(8))) short bf16x8;
typedef __attribute__((ext_vector_type(4))) float f32x4;

__device__ __forceinline__ float bf2f(unsigned short u) {
    union { unsigned int i; float f; } c; c.i = ((unsigned int)u) << 16; return c.f;
}
__device__ __forceinline__ unsigned short f2bf(float f) {
    union { float f; unsigned int i; } c; c.f = f;
    return (unsigned short)((c.i + 0x7fffu + ((c.i >> 16) & 1u)) >> 16);
}

__device__ __forceinline__ void gll16(const unsigned short* g, unsigned short* l) {
    __builtin_amdgcn_global_load_lds(
        (const __attribute__((address_space(1))) void*)g,
        (__attribute__((address_space(3))) void*)l, 16, 0, 0);
}

// f32 -> bf16 (RNE), vectorized x4. n4 = n/4.
__global__ __launch_bounds__(256) void cvt_f32_bf16_kernel(
    const float* __restrict__ src, unsigned short* __restrict__ dst, int n4)
{
    int idx = blockIdx.x * 256 + threadIdx.x;
    if (idx < n4) {
        float4 v = ((const float4*)src)[idx];
        ushort4 o;
        o.x = f2bf(v.x); o.y = f2bf(v.y); o.z = f2bf(v.z); o.w = f2bf(v.w);
        ((ushort4*)dst)[idx] = o;
    }
}

// W [R][Ncols] f32  ->  Wt [Ncols][R] bf16  (32x32 tiles via LDS)
__global__ __launch_bounds__(256) void cvt_transpose_kernel(
    const float* __restrict__ src, unsigned short* __restrict__ dst,
    int R, int Ncols)
{
    __shared__ unsigned short tile[32][36];
    const int r0 = blockIdx.y * 32, c0 = blockIdx.x * 32;
    const int t = threadIdx.x;
    const int rr = t >> 3, cq = (t & 7) * 4;
    float4 v = *(const float4*)(src + (size_t)(r0 + rr) * Ncols + c0 + cq);
    tile[rr][cq + 0] = f2bf(v.x); tile[rr][cq + 1] = f2bf(v.y);
    tile[rr][cq + 2] = f2bf(v.z); tile[rr][cq + 3] = f2bf(v.w);
    __syncthreads();
    const int cc = t >> 3, rq = (t & 7) * 4;
    ushort4 o;
    o.x = tile[rq + 0][cc]; o.y = tile[rq + 1][cc];
    o.z = tile[rq + 2][cc]; o.w = tile[rq + 3][cc];
    *(ushort4*)(dst + (size_t)(c0 + cc) * R + r0 + rq) = o;
}

// V slice of qkv [T][2048 + vcol] (bf16) -> vT [vcol][T] (bf16), 32x32 tiles.
__global__ __launch_bounds__(256) void transpose_v_kernel(
    const unsigned short* __restrict__ qkv, unsigned short* __restrict__ vT)
{
    __shared__ unsigned short tile[32][36];
    const int c0 = blockIdx.x * 32;   // vcol
    const int t0 = blockIdx.y * 32;   // token
    const int t = threadIdx.x;
    const int rr = t >> 3, cq = (t & 7) * 4;
    ushort4 v = *(const ushort4*)(qkv + (size_t)(t0 + rr) * QKVW + 2 * C_DIM + c0 + cq);
    tile[rr][cq + 0] = v.x; tile[rr][cq + 1] = v.y;
    tile[rr][cq + 2] = v.z; tile[rr][cq + 3] = v.w;
    __syncthreads();
    const int cc = t >> 3, rq = (t & 7) * 4;
    ushort4 o;
    o.x = tile[rq + 0][cc]; o.y = tile[rq + 1][cc];
    o.z = tile[rq + 2][cc]; o.w = tile[rq + 3][cc];
    *(ushort4*)(vT + (size_t)(c0 + cc) * T_SEQ + t0 + rq) = o;
}

// C[m,n] = sum_k A[m,k]*Bt[n,k] + bias[n]; m97 recipe (unchanged r7-r9).
template<int OUT_BF16>
__global__ __launch_bounds__(256) void gemm_nt_kernel(
    const unsigned short* __restrict__ A,    // [M,K]
    const unsigned short* __restrict__ Bt,   // [N,K]
    const float* __restrict__ bias,          // [N]
    void* __restrict__ Cv, int M, int N, int K)
{
    __shared__ unsigned short As[128 * 32];
    __shared__ unsigned short Bs[128 * 32];
    const int tid = threadIdx.x;
    const int w = tid >> 6, lane = tid & 63;
    const int quad = lane >> 4, r16 = lane & 15;
    const int m0 = blockIdx.y * 128, n0 = blockIdx.x * 128;
    const int wm = (w & 1) * 64, wn = (w >> 1) * 64;

    f32x4 acc[4][4];
    #pragma unroll
    for (int i = 0; i < 4; ++i)
        #pragma unroll
        for (int j = 0; j < 4; ++j) acc[i][j] = (f32x4){0.f, 0.f, 0.f, 0.f};

    const unsigned short* Ab = A + (size_t)m0 * K;
    const unsigned short* Bb = Bt + (size_t)n0 * K;

    for (int k0 = 0; k0 < K; k0 += 32) {
        __syncthreads();
        #pragma unroll
        for (int i = 0; i < 2; ++i) {
            const int chunk = w * 128 + i * 64 + lane;
            const int row = chunk >> 2, kc = (chunk & 3) * 8;
            gll16(Ab + (size_t)row * K + k0 + kc, &As[(w * 2 + i) * 512]);
            gll16(Bb + (size_t)row * K + k0 + kc, &Bs[(w * 2 + i) * 512]);
        }
        asm volatile("s_waitcnt vmcnt(0)" ::: "memory");
        __syncthreads();

        bf16x8 af[4], bf_[4];
        #pragma unroll
        for (int t = 0; t < 4; ++t) {
            af[t]  = *(const bf16x8*)&As[(wm + t * 16 + r16) * 32 + quad * 8];
            bf_[t] = *(const bf16x8*)&Bs[(wn + t * 16 + r16) * 32 + quad * 8];
        }
        #pragma unroll
        for (int mt = 0; mt < 4; ++mt)
            #pragma unroll
            for (int nt = 0; nt < 4; ++nt)
                acc[mt][nt] = __builtin_amdgcn_mfma_f32_16x16x32_bf16(
                    af[mt], bf_[nt], acc[mt][nt], 0, 0, 0);
    }

    #pragma unroll
    for (int nt = 0; nt < 4; ++nt) {
        const int col = n0 + wn + nt * 16 + r16;
        const float bv = bias[col];
        #pragma unroll
        for (int mt = 0; mt < 4; ++mt)
            #pragma unroll
            for (int reg = 0; reg < 4; ++reg) {
                const int row = m0 + wm + mt * 16 + quad * 4 + reg;
                if (OUT_BF16)
                    ((unsigned short*)Cv)[(size_t)row * N + col] = f2bf(acc[mt][nt][reg] + bv);
                else
                    ((float*)Cv)[(size_t)row * N + col] = acc[mt][nt][reg] + bv;
            }
    }
}

// MFMA flash attention, S^T formulation.
// S^T = K·Q^T (A=K natural rows, B=Q natural rows) -> C-layout col = q-row:
// each lane owns ONE q-row (n=lane&15), 16 score cols (g*16+quad*4+r).
// Softmax: in-lane tree + 2 shfls; single (m,l,alpha) scalar per lane.
// PV: O^T = V^T·P  (A=vT natural, B=P via tiny per-wave LDS round-trip:
// 8 ds_write_b32 + 2 ds_read_b128). O^T C-layout: col=q-row, row=d.
// One wave per (head, 16-row tile), full window sweep (<=7 64-col tiles),
// NO barriers, no cross-wave merge. Dense rows 0-31: 8-way split-K partials
// (slot=split) merged by attn_combine. XCD swizzle: h = bid&15.
#define PT_STRIDE 68
#define NSLOT 8
#define PROW 72
__global__ __launch_bounds__(256, 4) void sparse_attn_mfma(
    const unsigned short* __restrict__ qkv,
    const unsigned short* __restrict__ vT,
    unsigned short* __restrict__ y,
    float* __restrict__ part)
{
    __shared__ unsigned short Pt[4][16 * PT_STRIDE];
    const int tid = threadIdx.x;
    const int w = tid >> 6, lane = tid & 63;
    const int quad = lane >> 4, n = lane & 15;
    const int bid = blockIdx.x;

    int h, rowbase, split = -1, rt = 0;
    if (bid < 1024) {
        h = bid & 15;
        const int rtile = (bid >> 4) * 4 + w;
        if (rtile < 2) return;          // rows 0-31 handled by dense waves
        rowbase = rtile * 16;
    } else {
        const int idx = bid - 1024;     // [0,64)
        h = idx & 15;
        const int u = (idx >> 4) * 4 + w;   // [0,16)
        rt = u >> 3; split = u & 7;
        rowbase = rt * 16;
    }
    const bool dense = split >= 0;

    int wlo = 0, n_tiles;
    if (dense) n_tiles = 8;
    else {
        int t0 = (rowbase - WIN_HALF) & ~63; if (t0 < 64) t0 = 64;
        wlo = t0;
        int whi = rowbase + 16 + WIN_HALF; if (whi > T_SEQ) whi = T_SEQ;
        n_tiles = 1 + (whi - wlo + 63) / 64;
    }

    // Q B-frags: B[n=qrow][k=d] (natural rows)
    const unsigned short* qp = qkv + (size_t)(rowbase + n) * QKVW + h * 64 + quad * 8;
    bf16x8 q0 = *(const bf16x8*)qp;
    bf16x8 q1 = *(const bf16x8*)(qp + 32);

    const unsigned short* kb = qkv + C_DIM + h * 64;
    const unsigned short* vb = vT + (size_t)h * 64 * T_SEQ;
    unsigned short* myPt = Pt[w];

    f32x4 O[4];
    #pragma unroll
    for (int i = 0; i < 4; ++i) O[i] = (f32x4){0.f, 0.f, 0.f, 0.f};
    float m_run = -INFINITY, l_run = 0.f;
    const int row = rowbase + n;

    for (int it = 0; it < n_tiles; ++it) {
        const int c0 = dense ? (split * 512 + it * 64)
                             : (it == 0 ? 0 : wlo + (it - 1) * 64);

        // ---- K A-frags (natural rows): A[m=kcol][k=d] ----
        const unsigned short* kr = kb + (size_t)(c0 + n) * QKVW + quad * 8;
        bf16x8 klo[4], khi[4];
        #pragma unroll
        for (int g = 0; g < 4; ++g) {
            klo[g] = *(const bf16x8*)(kr + (size_t)(g * 16) * QKVW);
            khi[g] = *(const bf16x8*)(kr + (size_t)(g * 16) * QKVW + 32);
        }
        // ---- S^T = K Q^T ----
        const f32x4 Z = (f32x4){0.f, 0.f, 0.f, 0.f};
        f32x4 St[4];
        #pragma unroll
        for (int g = 0; g < 4; ++g) {
            St[g] = __builtin_amdgcn_mfma_f32_16x16x32_bf16(klo[g], q0, Z, 0, 0, 0);
            St[g] = __builtin_amdgcn_mfma_f32_16x16x32_bf16(khi[g], q1, St[g], 0, 0, 0);
        }
        // ---- V^T A-frags (issued early; consumed after softmax) ----
        const unsigned short* vr = vb + (size_t)n * T_SEQ + c0 + quad * 8;
        bf16x8 vlo[4], vhi[4];
        #pragma unroll
        for (int d = 0; d < 4; ++d) {
            vlo[d] = *(const bf16x8*)(vr + (size_t)(d * 16) * T_SEQ);
            vhi[d] = *(const bf16x8*)(vr + (size_t)(d * 16) * T_SEQ + 32);
        }

        // ---- scale + mask (in place) + lane max ----
        float mm = -INFINITY;
        #pragma unroll
        for (int g = 0; g < 4; ++g)
            #pragma unroll
            for (int r = 0; r < 4; ++r) {
                float v = St[g][r] * 0.125f;
                if (!dense) {
                    const int col = c0 + g * 16 + quad * 4 + r;
                    int dd = row - col; dd = dd < 0 ? -dd : dd;
                    if (!(col < GLOBAL_TOK || dd <= WIN_HALF)) v = -INFINITY;
                }
                St[g][r] = v;
                mm = fmaxf(mm, v);
            }
        mm = fmaxf(mm, __shfl_xor(mm, 16));
        mm = fmaxf(mm, __shfl_xor(mm, 32));
        const float mn = fmaxf(m_run, mm);
        const float mnf = (mn == -INFINITY) ? 0.f : mn;
        const float al = __expf(m_run - mnf);
        float rs = 0.f;
        #pragma unroll
        for (int g = 0; g < 4; ++g) {
            float e0 = __expf(St[g][0] - mnf);
            float e1 = __expf(St[g][1] - mnf);
            float e2 = __expf(St[g][2] - mnf);
            float e3 = __expf(St[g][3] - mnf);
            rs += (e0 + e1) + (e2 + e3);
            const unsigned int p01 = f2bf(e0) | ((unsigned int)f2bf(e1) << 16);
            const unsigned int p23 = f2bf(e2) | ((unsigned int)f2bf(e3) << 16);
            *(unsigned int*)&myPt[n * PT_STRIDE + g * 16 + quad * 4] = p01;
            *(unsigned int*)&myPt[n * PT_STRIDE + g * 16 + quad * 4 + 2] = p23;
        }
        rs += __shfl_xor(rs, 16);
        rs += __shfl_xor(rs, 32);
        l_run = l_run * al + rs;
        m_run = mn;
        #pragma unroll
        for (int d = 0; d < 4; ++d)
            #pragma unroll
            for (int r = 0; r < 4; ++r) O[d][r] *= al;

        asm volatile("s_waitcnt lgkmcnt(0)" ::: "memory");
        // ---- PV: O^T += V^T(A) x P(B) ----
        #pragma unroll
        for (int kg = 0; kg < 2; ++kg) {
            bf16x8 pf = *(const bf16x8*)&myPt[n * PT_STRIDE + kg * 32 + quad * 8];
            #pragma unroll
            for (int d = 0; d < 4; ++d)
                O[d] = __builtin_amdgcn_mfma_f32_16x16x32_bf16(
                    kg ? vhi[d] : vlo[d], pf, O[d], 0, 0, 0);
        }
    }

    if (!dense) {
        const float invL = 1.f / l_run;
        #pragma unroll
        for (int dblk = 0; dblk < 4; ++dblk)
            #pragma unroll
            for (int r = 0; r < 4; ++r)
                y[(size_t)row * C_DIM + h * 64 + dblk * 16 + quad * 4 + r] =
                    f2bf(O[dblk][r] * invL);
    } else {
        float* pb = part + ((size_t)(h * 2 + rt) * NSLOT + split) * 16 * PROW;
        #pragma unroll
        for (int dblk = 0; dblk < 4; ++dblk)
            #pragma unroll
            for (int r = 0; r < 4; ++r)
                pb[n * PROW + dblk * 16 + quad * 4 + r] = O[dblk][r];
        if (quad == 0) {
            pb[n * PROW + 64] = m_run;
            pb[n * PROW + 65] = l_run;
        }
    }
}

// Merge NSLOT partials per (head, 16-row tile) -> y rows 0..31.
__global__ __launch_bounds__(64) void attn_combine(
    const float* __restrict__ part, unsigned short* __restrict__ y)
{
    const int d = threadIdx.x;
    const int h = blockIdx.x >> 1, rt = blockIdx.x & 1;
    const float* base = part + (size_t)(h * 2 + rt) * NSLOT * 16 * PROW;
    for (int row = 0; row < 16; ++row) {
        float M = -INFINITY;
        for (int sl = 0; sl < NSLOT; ++sl)
            M = fmaxf(M, base[(size_t)sl * 16 * PROW + row * PROW + 64]);
        float L = 0.f, Od = 0.f;
        for (int sl = 0; sl < NSLOT; ++sl) {
            const float* p = base + (size_t)sl * 16 * PROW + row * PROW;
            const float s = __expf(p[64] - M);
            L += p[65] * s;
            Od += p[d] * s;
        }
        y[(size_t)(rt * 16 + row) * C_DIM + h * 64 + d] = f2bf(Od / L);
    }
}

extern "C" void kernel_launch(void* const* d_in, const int* in_sizes, int n_in,
                              void* d_out, int out_size, void* d_ws, size_t ws_size,
                              hipStream_t stream) {
    const float* x  = (const float*)d_in[0];
    const float* Wa = (const float*)d_in[1];
    const float* ba = (const float*)d_in[2];
    const float* Wp = (const float*)d_in[3];
    const float* bp = (const float*)d_in[4];
    float* out = (float*)d_out;

    // ws (ushort units): xb 4M, Wabt 3M, Wpbt 1M, qkv 12M, yat 4M = 48 MiB
    unsigned short* xb   = (unsigned short*)d_ws;                   // [4096,1024]
    unsigned short* Wabt = xb   + (size_t)T_SEQ * C_DIM;            // [3072,1024]
    unsigned short* Wpbt = Wabt + (size_t)C_DIM * QKVW;             // [1024,1024]
    unsigned short* qkv  = Wpbt + (size_t)C_DIM * C_DIM;            // [4096,3072]
    unsigned short* yat  = qkv  + (size_t)T_SEQ * QKVW;             // [4096,1024]
    // overlays (dead after gemm1): vT on xb (8 MiB), part on Wabt (2.4 MB)
    unsigned short* vT = xb;
    float* part = (float*)Wabt;

    const int n_x = T_SEQ * C_DIM;
    cvt_f32_bf16_kernel<<<n_x / 4 / 256, 256, 0, stream>>>(x, xb, n_x / 4);
    cvt_transpose_kernel<<<dim3(QKVW / 32, C_DIM / 32), 256, 0, stream>>>(
        Wa, Wabt, C_DIM, QKVW);
    cvt_transpose_kernel<<<dim3(C_DIM / 32, C_DIM / 32), 256, 0, stream>>>(
        Wp, Wpbt, C_DIM, C_DIM);

    gemm_nt_kernel<1><<<dim3(QKVW / 128, T_SEQ / 128), 256, 0, stream>>>(
        xb, Wabt, ba, qkv, T_SEQ, QKVW, C_DIM);

    transpose_v_kernel<<<dim3(C_DIM / 32, T_SEQ / 32), 256, 0, stream>>>(qkv, vT);

    const int nBlocks = 1024 + 64;   // normal + dense split-K
    sparse_attn_mfma<<<nBlocks, 256, 0, stream>>>(qkv, vT, yat, part);
    attn_combine<<<H_HEADS * 2, 64, 0, stream>>>(part, yat);

    gemm_nt_kernel<0><<<dim3(C_DIM / 128, T_SEQ / 128), 256, 0, stream>>>(
        yat, Wpbt, bp, out, T_SEQ, C_DIM, C_DIM);
}